// Round 8
// baseline (711.718 us; speedup 1.0000x reference)
//
#include <hip/hip_runtime.h>

typedef short bf16x8 __attribute__((ext_vector_type(8)));
typedef float f32x4 __attribute__((ext_vector_type(4)));
typedef unsigned uint4v __attribute__((ext_vector_type(4)));

#define NROWS 131072L
#define DIN 1024
#define DEMB 512
#define NEXT 640   // extended B rows: 512 emb + 34 folded-head + 94 zero

// f32 -> bf16 RNE bit-twiddle (one-time prep kernels).
__device__ __forceinline__ unsigned short f2bf(float f) {
  unsigned u = __float_as_uint(f);
  u += 0x7FFFu + ((u >> 16) & 1u);
  return (unsigned short)(u >> 16);
}

// Pack two f32 -> two bf16 (round-half-up): 2 adds + 1 v_perm_b32 (R5/R6-proven).
__device__ __forceinline__ unsigned pkhi(float a, float b) {
  unsigned ua = __float_as_uint(a) + 0x8000u;
  unsigned ub = __float_as_uint(b) + 0x8000u;
  return __builtin_amdgcn_perm(ub, ua, 0x07060302u);
}

__device__ __forceinline__ float softplusf(float v) {
  return fmaxf(v, 0.f) + log1pf(expf(-fabsf(v)));
}

// ---------- kernel 0: Wb (1024x512 f32) -> WbT rows 0..511 (bf16, k-contig) ----------
__global__ __launch_bounds__(256) void wb_transpose(const float* __restrict__ Wb,
                                                    unsigned short* __restrict__ WbT) {
  int g = blockIdx.x * 256 + threadIdx.x;
  int n = g & 511;
  int kb = g >> 9;
  unsigned short tmp[8];
#pragma unroll
  for (int j = 0; j < 8; ++j)
    tmp[j] = f2bf(Wb[(kb * 8 + j) * DEMB + n]);
  uint4 v;
  v.x = (unsigned)tmp[0] | ((unsigned)tmp[1] << 16);
  v.y = (unsigned)tmp[2] | ((unsigned)tmp[3] << 16);
  v.z = (unsigned)tmp[4] | ((unsigned)tmp[5] << 16);
  v.w = (unsigned)tmp[6] | ((unsigned)tmp[7] << 16);
  *(uint4*)(WbT + (long)n * DIN + kb * 8) = v;
}

// ---------- kernel 0b: zero rows 546..639 of WbT_ext ----------
__global__ void zero_tail(unsigned* __restrict__ p) {
  p[blockIdx.x * 256 + threadIdx.x] = 0u;
}

// ---------- kernel 0c: WbT rows 512..545 = (Wb @ W34)^T  (head-weight fold) ----------
__global__ __launch_bounds__(256) void wfold_rows(const float* __restrict__ Wb,
                                                  const float* __restrict__ Wp,
                                                  const float* __restrict__ Ws,
                                                  unsigned short* __restrict__ WbT) {
  int w = threadIdx.x >> 6, lane = threadIdx.x & 63;
  int k = blockIdx.x * 4 + w;
  if (lane >= 34) return;
  const float* src;
  if (lane < 2) src = Wp + lane;
  else { int s = (lane - 2) >> 1; src = Ws + s * 1024 + (lane & 1); }
  const float* wrow = Wb + (long)k * DEMB;
  float acc = 0.f;
#pragma unroll 8
  for (int d = 0; d < DEMB; ++d) acc = fmaf(wrow[d], src[2 * d], acc);
  WbT[(long)(512 + lane) * DIN + k] = f2bf(acc);
}

// ---------- kernel 0d: bfold[j] = bb @ W34[:,j] + bias34[j] ----------
__global__ void bfold_k(const float* __restrict__ bb, const float* __restrict__ Wp,
                        const float* __restrict__ bp, const float* __restrict__ Ws,
                        const float* __restrict__ bs, float* __restrict__ bf) {
  int j = threadIdx.x;
  if (j >= 34) return;
  const float* src; float bias;
  if (j < 2) { src = Wp + j; bias = bp[j]; }
  else { int s = (j - 2) >> 1; src = Ws + s * 1024 + (j & 1); bias = bs[s * 2 + (j & 1)]; }
  float acc = bias;
  for (int d = 0; d < DEMB; ++d) acc = fmaf(bb[d], src[2 * d], acc);
  bf[j] = acc;
}

// ---------- kernel 1: fused GEMM ----------
// 128x128 tile, BK=32, 2x2 waves. A: DIRECT global->reg->pkhi->MFMA (never
// touches LDS — kills the LDS-BW oversubscription: 72KB -> 24KB per block-
// tile). A reg-double-buffered 1 tile ahead. B: gload_lds 2-slot, counted
// vmcnt(8) at barrier (FIFO: stageB issued first -> drains exactly stageB,
// keeps the 8 A-loads in flight across the barrier).
__global__ __launch_bounds__(256, 3) void gemm_fused(
    const float* __restrict__ x, const unsigned short* __restrict__ wbt,
    const float* __restrict__ bb, const int* __restrict__ sid,
    const float* __restrict__ bfold, float* __restrict__ out) {
  __shared__ __align__(16) char SM[18432];   // B slots 2x8KB; head overlay 17.5KB
  char* const B0 = SM;
  char* const B1 = SM + 8192;

  const int t = threadIdx.x;
  const int lane = t & 63;
  const int wid = t >> 6;
  const int wm = wid >> 1, wn = wid & 1;

  // XCD swizzle: 5120 blocks (%8==0); 5 consecutive swz share one mtile/XCD.
  const int bid = blockIdx.x;
  const int swz = (bid & 7) * 640 + (bid >> 3);
  const int mtile = swz / 5;
  const int ntile = swz - mtile * 5;
  const long m0 = (long)mtile * 128;
  const int n0 = ntile * 128;

  const int l15 = lane & 15, lg = lane >> 4;

  // ---- A: direct per-wave global loads matching the MFMA A-frag layout ----
  // af row = l15 (+mi*16 +wm*64), k-chunk = lg*8 (+tile*32)
  const float* xw = x + (m0 + wm * 64 + l15) * DIN + lg * 8;

  // ---- B stage (bf16, gload_lds, pre-swizzled source; R6-proven) ----
  const int bn = wid * 16 + (lane >> 2);
  const int bsg = (lane & 3) ^ ((lane >> 3) & 3);
  const unsigned short* bsrc = wbt + (long)(n0 + bn) * DIN + bsg * 8;

  // B frag reads: granule = lg ^ ((l15>>1)&3), 64B rows (conflict-free)
  const int kgoB = ((lg ^ ((l15 >> 1) & 3)) << 4);
  const int brdrow = (wn * 64 + l15) * 64;

  f32x4 acc[4][4] = {};
  f32x4 arC[4][2], arN[4][2];

  auto stageB = [&](char* Bw, int k0) {
#pragma unroll
    for (int i = 0; i < 2; ++i) {
      const unsigned short* gp = bsrc + (long)i * 64 * DIN + k0;
      __builtin_amdgcn_global_load_lds(
          (const __attribute__((address_space(1))) void*)gp,
          (__attribute__((address_space(3))) void*)(Bw + i * 4096 + wid * 1024),
          16, 0, 0);
    }
  };
  auto loadA = [&](f32x4 (*d)[2], int k0) {
#pragma unroll
    for (int mi = 0; mi < 4; ++mi) {
      const float* p = xw + (long)mi * 16 * DIN + k0;
      d[mi][0] = *(const f32x4*)p;
      d[mi][1] = *(const f32x4*)(p + 4);
    }
  };
  auto compute = [&](const char* Bc, f32x4 (*a)[2]) {
    bf16x8 af[4], bfv[4];
#pragma unroll
    for (int i = 0; i < 4; ++i) {
      uint4v u;
      u[0] = pkhi(a[i][0][0], a[i][0][1]);
      u[1] = pkhi(a[i][0][2], a[i][0][3]);
      u[2] = pkhi(a[i][1][0], a[i][1][1]);
      u[3] = pkhi(a[i][1][2], a[i][1][3]);
      af[i] = __builtin_bit_cast(bf16x8, u);
      bfv[i] = *(const bf16x8*)(Bc + brdrow + i * 1024 + kgoB);
    }
#pragma unroll
    for (int mi = 0; mi < 4; ++mi)
#pragma unroll
      for (int ni = 0; ni < 4; ++ni)
        acc[mi][ni] = __builtin_amdgcn_mfma_f32_16x16x32_bf16(af[mi], bfv[ni],
                                                             acc[mi][ni], 0, 0, 0);
  };
  // body t: stageB(t+1) first (oldest), loadA(t+1), compute(t);
  // vmcnt(8) drains exactly stageB(t+1), keeps loadA(t+1) flying.
  auto body = [&](char* Bc, char* Bw, f32x4 (*ac)[2], f32x4 (*an)[2], int tt) {
    stageB(Bw, (tt + 1) * 32);
    loadA(an, (tt + 1) * 32);
    compute(Bc, ac);
    __builtin_amdgcn_sched_barrier(0);
    asm volatile("s_waitcnt vmcnt(8) lgkmcnt(0)" ::: "memory");
    __builtin_amdgcn_sched_barrier(0);
    __builtin_amdgcn_s_barrier();
  };

  // prologue: B(0) staged+drained; A(0) loads left in flight (8 newest)
  stageB(B0, 0);
  loadA(arC, 0);
  __builtin_amdgcn_sched_barrier(0);
  asm volatile("s_waitcnt vmcnt(8) lgkmcnt(0)" ::: "memory");
  __builtin_amdgcn_sched_barrier(0);
  __builtin_amdgcn_s_barrier();

#pragma unroll 1
  for (int tb = 0; tb < 30; tb += 2) {
    body(B0, B1, arC, arN, tb);
    body(B1, B0, arN, arC, tb + 1);
  }
  body(B0, B1, arC, arN, 30);   // stages B(31), loads A(31), computes tile 30
  compute(B1, arN);             // tile 31 (compiler waits A(31) loads)

  // ---- epilogue ----
  if (ntile < 4) {
    const int colg = n0 + wn * 64 + l15;
    float bbv[4];
#pragma unroll
    for (int ni = 0; ni < 4; ++ni) bbv[ni] = bb[colg + ni * 16];
#pragma unroll
    for (int mi = 0; mi < 4; ++mi) {
      const long rbase = m0 + wm * 64 + mi * 16 + lg * 4;
#pragma unroll
      for (int ni = 0; ni < 4; ++ni)
#pragma unroll
        for (int r = 0; r < 4; ++r)
          out[(rbase + r) * DEMB + colg + ni * 16] = acc[mi][ni][r] + bbv[ni];
    }
  } else {
    // head tile: acc cols 0..33 are x@Wfold; gather selected cols via LDS
    __syncthreads();
    float* hl = (float*)SM;          // [128][35] f32 = 17.5 KiB
    if (wn == 0) {
#pragma unroll
      for (int ni = 0; ni < 3; ++ni) {
        if (ni * 16 + 0 >= 35) continue;
#pragma unroll
        for (int mi = 0; mi < 4; ++mi)
#pragma unroll
          for (int r = 0; r < 4; ++r) {
            int row = wm * 64 + mi * 16 + lg * 4 + r;
            int col = l15 + ni * 16;
            if (col < 35) hl[row * 35 + col] = acc[mi][ni][r];
          }
      }
    }
    __syncthreads();
    if (t < 128) {
      const long row = m0 + t;
      const int s = sid[row];
      const float v0 = hl[t * 35 + 0] + bfold[0];
      const float v1 = hl[t * 35 + 1] + bfold[1];
      const float v2 = hl[t * 35 + 2 + 2 * s] + bfold[2 + 2 * s];
      const float v3 = hl[t * 35 + 3 + 2 * s] + bfold[3 + 2 * s];
      float* hp = out + NROWS * DEMB;
      hp[row] = v0;
      hp[NROWS + row] = softplusf(v1) + 0.001f;
      hp[2 * NROWS + row] = v2;
      hp[3 * NROWS + row] = softplusf(v3) + 0.001f;
    }
  }
}

extern "C" void kernel_launch(void* const* d_in, const int* in_sizes, int n_in,
                              void* d_out, int out_size, void* d_ws, size_t ws_size,
                              hipStream_t stream) {
  const float* x  = (const float*)d_in[0];
  const int* sid  = (const int*)d_in[1];
  const float* Wb = (const float*)d_in[2];
  const float* bb = (const float*)d_in[3];
  const float* Wp = (const float*)d_in[4];
  const float* bp = (const float*)d_in[5];
  const float* Ws = (const float*)d_in[6];
  const float* bs = (const float*)d_in[7];
  float* out = (float*)d_out;
  unsigned short* WbT = (unsigned short*)d_ws;            // 640*1024 bf16 = 1.25 MiB
  float* bfoldp = (float*)(WbT + (long)NEXT * DIN);       // 34 f32

  wb_transpose<<<256, 256, 0, stream>>>(Wb, WbT);
  zero_tail<<<188, 256, 0, stream>>>((unsigned*)(WbT + 546 * DIN));
  wfold_rows<<<256, 256, 0, stream>>>(Wb, Wp, Ws, WbT);
  bfold_k<<<1, 64, 0, stream>>>(bb, Wp, bp, Ws, bs, bfoldp);
  gemm_fused<<<5120, 256, 0, stream>>>(x, WbT, bb, sid, bfoldp, out);
}

// Round 9
// 406.787 us; speedup vs baseline: 1.7496x; 1.7496x over previous
//
#include <hip/hip_runtime.h>

typedef short bf16x8 __attribute__((ext_vector_type(8)));
typedef float f32x4 __attribute__((ext_vector_type(4)));

#define NROWS 131072L
#define DIN 1024
#define DEMB 512
#define NEXT 640   // extended B rows: 512 emb + 34 folded-head + zero tail

// f32 -> bf16 RNE bit-twiddle (one-time prep kernels).
__device__ __forceinline__ unsigned short f2bf(float f) {
  unsigned u = __float_as_uint(f);
  u += 0x7FFFu + ((u >> 16) & 1u);
  return (unsigned short)(u >> 16);
}

// Pack two f32 -> two bf16 (round-half-up): 2 adds + 1 v_perm_b32 (R5/R6-proven).
__device__ __forceinline__ unsigned pkhi(float a, float b) {
  unsigned ua = __float_as_uint(a) + 0x8000u;
  unsigned ub = __float_as_uint(b) + 0x8000u;
  return __builtin_amdgcn_perm(ub, ua, 0x07060302u);
}

__device__ __forceinline__ float softplusf(float v) {
  return fmaxf(v, 0.f) + log1pf(expf(-fabsf(v)));
}

// ---------- kernel 0: Wb (1024x512 f32) -> WbT rows 0..511 (bf16, k-contig) ----------
__global__ __launch_bounds__(256) void wb_transpose(const float* __restrict__ Wb,
                                                    unsigned short* __restrict__ WbT) {
  int g = blockIdx.x * 256 + threadIdx.x;
  int n = g & 511;
  int kb = g >> 9;
  unsigned short tmp[8];
#pragma unroll
  for (int j = 0; j < 8; ++j)
    tmp[j] = f2bf(Wb[(kb * 8 + j) * DEMB + n]);
  uint4 v;
  v.x = (unsigned)tmp[0] | ((unsigned)tmp[1] << 16);
  v.y = (unsigned)tmp[2] | ((unsigned)tmp[3] << 16);
  v.z = (unsigned)tmp[4] | ((unsigned)tmp[5] << 16);
  v.w = (unsigned)tmp[6] | ((unsigned)tmp[7] << 16);
  *(uint4*)(WbT + (long)n * DIN + kb * 8) = v;
}

// ---------- kernel 0b: zero rows 546..639 of WbT_ext ----------
__global__ void zero_tail(unsigned* __restrict__ p) {
  p[blockIdx.x * 256 + threadIdx.x] = 0u;
}

// ---------- kernel 0c: WbT rows 512..545 = (Wb @ W34)^T  (head-weight fold) ----------
__global__ __launch_bounds__(256) void wfold_rows(const float* __restrict__ Wb,
                                                  const float* __restrict__ Wp,
                                                  const float* __restrict__ Ws,
                                                  unsigned short* __restrict__ WbT) {
  int w = threadIdx.x >> 6, lane = threadIdx.x & 63;
  int k = blockIdx.x * 4 + w;
  if (lane >= 34) return;
  const float* src;
  if (lane < 2) src = Wp + lane;
  else { int s = (lane - 2) >> 1; src = Ws + s * 1024 + (lane & 1); }
  const float* wrow = Wb + (long)k * DEMB;
  float acc = 0.f;
#pragma unroll 8
  for (int d = 0; d < DEMB; ++d) acc = fmaf(wrow[d], src[2 * d], acc);
  WbT[(long)(512 + lane) * DIN + k] = f2bf(acc);
}

// ---------- kernel 0d: bfold[j] = bb @ W34[:,j] + bias34[j] ----------
__global__ void bfold_k(const float* __restrict__ bb, const float* __restrict__ Wp,
                        const float* __restrict__ bp, const float* __restrict__ Ws,
                        const float* __restrict__ bs, float* __restrict__ bf) {
  int j = threadIdx.x;
  if (j >= 34) return;
  const float* src; float bias;
  if (j < 2) { src = Wp + j; bias = bp[j]; }
  else { int s = (j - 2) >> 1; src = Ws + s * 1024 + (j & 1); bias = bs[s * 2 + (j & 1)]; }
  float acc = bias;
  for (int d = 0; d < DEMB; ++d) acc = fmaf(bb[d], src[2 * d], acc);
  bf[j] = acc;
}

// ---------- kernel 1: fused GEMM ----------
// 128x64 tile, BK=32, 4 waves (2 wm x 2 wn), wave-tile 64x32 (acc 4x2 = 32
// AGPR). Same R6-proven body: A reg-staged f32->pkhi->LDS (swizzled), B via
// gload_lds pre-swizzled, counted vmcnt keeps next-next A-loads in flight.
// Regs ~110 unified -> 4 waves/EU; LDS 24KB -> occupancy 16 waves/CU (vs R6 12).
__global__ __launch_bounds__(256, 4) void gemm_fused(
    const float* __restrict__ x, const unsigned short* __restrict__ wbt,
    const float* __restrict__ bb, const int* __restrict__ sid,
    const float* __restrict__ bfold, float* __restrict__ out) {
  __shared__ __align__(16) char SM[24576];   // As0|As1 (8KB ea) | B0|B1 (4KB ea)
  char* const As0 = SM;
  char* const As1 = SM + 8192;
  char* const B0  = SM + 16384;
  char* const B1  = SM + 20480;

  const int t = threadIdx.x;
  const int lane = t & 63;
  const int wid = t >> 6;
  const int wm = wid >> 1, wn = wid & 1;

  // XCD swizzle: 9216 blocks (%8==0); 9 consecutive swz (one mtile) per XCD.
  const int bid = blockIdx.x;
  const int swz = (bid & 7) * 1152 + (bid >> 3);
  const int mtile = swz / 9;
  const int ntile = swz - mtile * 9;        // 0..7 emb, 8 = head
  const long m0 = (long)mtile * 128;
  const int n0 = ntile * 64;

  // ---- A staging (R6-proven): row = t>>3 (+32p), float4 kc = t&7 ----
  const int akc = t & 7;
  const int abyte = (t >> 3) * 64 + ((((akc >> 1) ^ ((t >> 4) & 3)) << 4)) + (akc & 1) * 8;
  const float* xbase = x + (m0 + (t >> 3)) * DIN + akc * 4;

  // ---- B staging: 1 gload_lds/thread; dst granule t -> n = t>>2, phys gk = t&3,
  //      src granule = (t&3) ^ ((n>>1)&3) = (t&3)^((t>>3)&3) (R6 algebra) ----
  const unsigned short* bsrc =
      wbt + (long)(n0 + (t >> 2)) * DIN + ((t & 3) ^ ((t >> 3) & 3)) * 8;

  // ---- fragment reads: granule = lg ^ ((l15>>1)&3), 64B rows ----
  const int l15 = lane & 15, lg = lane >> 4;
  const int kgo = ((lg ^ ((l15 >> 1) & 3)) << 4);
  const int ardrow = (wm * 64 + l15) * 64;
  const int brdrow = (wn * 32 + l15) * 64;

  f32x4 acc[4][2] = {};
  float4 aregA[4], aregB[4];

  auto loadA_A = [&](int k0) {
#pragma unroll
    for (int p = 0; p < 4; ++p)
      aregA[p] = *(const float4*)(xbase + (long)p * 32 * DIN + k0);
  };
  auto loadA_B = [&](int k0) {
#pragma unroll
    for (int p = 0; p < 4; ++p)
      aregB[p] = *(const float4*)(xbase + (long)p * 32 * DIN + k0);
  };
  auto stageB = [&](char* Bw, int k0) {
    const unsigned short* gp = bsrc + k0;
    __builtin_amdgcn_global_load_lds(
        (const __attribute__((address_space(1))) void*)gp,
        (__attribute__((address_space(3))) void*)(Bw + wid * 1024),
        16, 0, 0);
  };
  auto writeA_0A = [&]() {
    char* base = As0;
#pragma unroll
    for (int p = 0; p < 4; ++p) {
      uint2 v; v.x = pkhi(aregA[p].x, aregA[p].y); v.y = pkhi(aregA[p].z, aregA[p].w);
      *(uint2*)(base + abyte + p * 2048) = v;
    }
  };
  auto writeA_1B = [&]() {
    char* base = As1;
#pragma unroll
    for (int p = 0; p < 4; ++p) {
      uint2 v; v.x = pkhi(aregB[p].x, aregB[p].y); v.y = pkhi(aregB[p].z, aregB[p].w);
      *(uint2*)(base + abyte + p * 2048) = v;
    }
  };
  auto compute = [&](const char* Ab, const char* Bb) {
    bf16x8 af[4], bfv[2];
#pragma unroll
    for (int i = 0; i < 4; ++i)
      af[i] = *(const bf16x8*)(Ab + ardrow + i * 1024 + kgo);
#pragma unroll
    for (int i = 0; i < 2; ++i)
      bfv[i] = *(const bf16x8*)(Bb + brdrow + i * 1024 + kgo);
#pragma unroll
    for (int mi = 0; mi < 4; ++mi)
#pragma unroll
      for (int ni = 0; ni < 2; ++ni)
        acc[mi][ni] = __builtin_amdgcn_mfma_f32_16x16x32_bf16(af[mi], bfv[ni],
                                                             acc[mi][ni], 0, 0, 0);
  };

  // prologue: tile0 staged+written; A(1) loads left in flight
  stageB(B0, 0);
  loadA_A(0);
  writeA_0A();                      // compiler-inserted wait for A(0) loads
  loadA_B(32);
  __builtin_amdgcn_sched_barrier(0);
  asm volatile("s_waitcnt vmcnt(4) lgkmcnt(0)" ::: "memory");
  __builtin_amdgcn_sched_barrier(0);
  __builtin_amdgcn_s_barrier();

#pragma unroll 1
  for (int tb = 0; tb < 30; tb += 2) {
    // even tile tb: compute from As0/B0; stage B(tb+1); prefetch A(tb+2)
    stageB(B1, (tb + 1) * 32);
    loadA_A((tb + 2) * 32);
    compute(As0, B0);
    writeA_1B();                    // waits A(tb+1) (oldest 4) via compiler vmcnt(5)
    __builtin_amdgcn_sched_barrier(0);
    asm volatile("s_waitcnt vmcnt(4) lgkmcnt(0)" ::: "memory");   // drain stageB, keep A(tb+2)
    __builtin_amdgcn_sched_barrier(0);
    __builtin_amdgcn_s_barrier();
    // odd tile tb+1
    stageB(B0, (tb + 2) * 32);
    loadA_B((tb + 3) * 32);
    compute(As1, B1);
    writeA_0A();
    __builtin_amdgcn_sched_barrier(0);
    asm volatile("s_waitcnt vmcnt(4) lgkmcnt(0)" ::: "memory");
    __builtin_amdgcn_sched_barrier(0);
    __builtin_amdgcn_s_barrier();
  }
  // tile 30: stage B(31); compute; write A(31); full drain
  stageB(B1, 31 * 32);
  compute(As0, B0);
  writeA_1B();
  __builtin_amdgcn_sched_barrier(0);
  asm volatile("s_waitcnt vmcnt(0) lgkmcnt(0)" ::: "memory");
  __builtin_amdgcn_sched_barrier(0);
  __builtin_amdgcn_s_barrier();
  // tile 31
  compute(As1, B1);

  // ---- epilogue ----
  if (ntile < 8) {
    const int colg = n0 + wn * 32 + l15;
    float bbv[2];
#pragma unroll
    for (int ni = 0; ni < 2; ++ni) bbv[ni] = bb[colg + ni * 16];
#pragma unroll
    for (int mi = 0; mi < 4; ++mi) {
      const long rbase = m0 + wm * 64 + mi * 16 + lg * 4;
#pragma unroll
      for (int ni = 0; ni < 2; ++ni)
#pragma unroll
        for (int r = 0; r < 4; ++r)
          out[(rbase + r) * DEMB + colg + ni * 16] = acc[mi][ni][r] + bbv[ni];
    }
  } else {
    // head tile: acc cols 0..33 (of 64) are x@Wfold; gather selected cols per row
    __syncthreads();
    float* hl = (float*)SM;          // [128][35] f32 = 17.5 KiB (stride 35: conflict-free gather)
    if (wn == 0 || (wn == 1 && l15 < 2)) {
#pragma unroll
      for (int ni = 0; ni < 2; ++ni) {
        int col = wn * 32 + ni * 16 + l15;
        if (col < 34) {
#pragma unroll
          for (int mi = 0; mi < 4; ++mi)
#pragma unroll
            for (int r = 0; r < 4; ++r) {
              int row = wm * 64 + mi * 16 + lg * 4 + r;
              hl[row * 35 + col] = acc[mi][ni][r];
            }
        }
      }
    }
    __syncthreads();
    if (t < 128) {
      const long row = m0 + t;
      const int s = sid[row];
      const float v0 = hl[t * 35 + 0] + bfold[0];
      const float v1 = hl[t * 35 + 1] + bfold[1];
      const float v2 = hl[t * 35 + 2 + 2 * s] + bfold[2 + 2 * s];
      const float v3 = hl[t * 35 + 3 + 2 * s] + bfold[3 + 2 * s];
      float* hp = out + NROWS * DEMB;
      hp[row] = v0;
      hp[NROWS + row] = softplusf(v1) + 0.001f;
      hp[2 * NROWS + row] = v2;
      hp[3 * NROWS + row] = softplusf(v3) + 0.001f;
    }
  }
}

extern "C" void kernel_launch(void* const* d_in, const int* in_sizes, int n_in,
                              void* d_out, int out_size, void* d_ws, size_t ws_size,
                              hipStream_t stream) {
  const float* x  = (const float*)d_in[0];
  const int* sid  = (const int*)d_in[1];
  const float* Wb = (const float*)d_in[2];
  const float* bb = (const float*)d_in[3];
  const float* Wp = (const float*)d_in[4];
  const float* bp = (const float*)d_in[5];
  const float* Ws = (const float*)d_in[6];
  const float* bs = (const float*)d_in[7];
  float* out = (float*)d_out;
  unsigned short* WbT = (unsigned short*)d_ws;            // 640*1024 bf16 = 1.25 MiB
  float* bfoldp = (float*)(WbT + (long)NEXT * DIN);       // 34 f32

  wb_transpose<<<256, 256, 0, stream>>>(Wb, WbT);
  zero_tail<<<188, 256, 0, stream>>>((unsigned*)(WbT + 546 * DIN));
  wfold_rows<<<256, 256, 0, stream>>>(Wb, Wp, Ws, WbT);
  bfold_k<<<1, 64, 0, stream>>>(bb, Wp, bp, Ws, bs, bfoldp);
  gemm_fused<<<9216, 256, 0, stream>>>(x, WbT, bb, sid, bfoldp, out);
}

// Round 10
// 351.236 us; speedup vs baseline: 2.0263x; 1.1582x over previous
//
#include <hip/hip_runtime.h>

typedef short bf16x8 __attribute__((ext_vector_type(8)));
typedef float f32x4 __attribute__((ext_vector_type(4)));

#define NROWS 131072L
#define DIN 1024
#define DEMB 512
#define NEXT 640   // extended B rows: 512 emb + 34 folded-head + zero tail

// f32 -> bf16 RNE bit-twiddle (one-time prep kernels).
__device__ __forceinline__ unsigned short f2bf(float f) {
  unsigned u = __float_as_uint(f);
  u += 0x7FFFu + ((u >> 16) & 1u);
  return (unsigned short)(u >> 16);
}

// Pack two f32 -> two bf16 (round-half-up): 2 adds + 1 v_perm_b32 (R5/R6-proven).
__device__ __forceinline__ unsigned pkhi(float a, float b) {
  unsigned ua = __float_as_uint(a) + 0x8000u;
  unsigned ub = __float_as_uint(b) + 0x8000u;
  return __builtin_amdgcn_perm(ub, ua, 0x07060302u);
}

__device__ __forceinline__ float softplusf(float v) {
  return fmaxf(v, 0.f) + log1pf(expf(-fabsf(v)));
}

// ---------- kernel 0: Wb (1024x512 f32) -> WbT rows 0..511 (bf16, k-contig) ----------
__global__ __launch_bounds__(256) void wb_transpose(const float* __restrict__ Wb,
                                                    unsigned short* __restrict__ WbT) {
  int g = blockIdx.x * 256 + threadIdx.x;
  int n = g & 511;
  int kb = g >> 9;
  unsigned short tmp[8];
#pragma unroll
  for (int j = 0; j < 8; ++j)
    tmp[j] = f2bf(Wb[(kb * 8 + j) * DEMB + n]);
  uint4 v;
  v.x = (unsigned)tmp[0] | ((unsigned)tmp[1] << 16);
  v.y = (unsigned)tmp[2] | ((unsigned)tmp[3] << 16);
  v.z = (unsigned)tmp[4] | ((unsigned)tmp[5] << 16);
  v.w = (unsigned)tmp[6] | ((unsigned)tmp[7] << 16);
  *(uint4*)(WbT + (long)n * DIN + kb * 8) = v;
}

// ---------- kernel 0b: zero rows 546..639 of WbT_ext ----------
__global__ void zero_tail(unsigned* __restrict__ p) {
  p[blockIdx.x * 256 + threadIdx.x] = 0u;
}

// ---------- kernel 0c: WbT rows 512..545 = (Wb @ W34)^T  (head-weight fold) ----------
__global__ __launch_bounds__(256) void wfold_rows(const float* __restrict__ Wb,
                                                  const float* __restrict__ Wp,
                                                  const float* __restrict__ Ws,
                                                  unsigned short* __restrict__ WbT) {
  int w = threadIdx.x >> 6, lane = threadIdx.x & 63;
  int k = blockIdx.x * 4 + w;
  if (lane >= 34) return;
  const float* src;
  if (lane < 2) src = Wp + lane;
  else { int s = (lane - 2) >> 1; src = Ws + s * 1024 + (lane & 1); }
  const float* wrow = Wb + (long)k * DEMB;
  float acc = 0.f;
#pragma unroll 8
  for (int d = 0; d < DEMB; ++d) acc = fmaf(wrow[d], src[2 * d], acc);
  WbT[(long)(512 + lane) * DIN + k] = f2bf(acc);
}

// ---------- kernel 0d: bfold[j] = bb @ W34[:,j] + bias34[j] ----------
__global__ void bfold_k(const float* __restrict__ bb, const float* __restrict__ Wp,
                        const float* __restrict__ bp, const float* __restrict__ Ws,
                        const float* __restrict__ bs, float* __restrict__ bf) {
  int j = threadIdx.x;
  if (j >= 34) return;
  const float* src; float bias;
  if (j < 2) { src = Wp + j; bias = bp[j]; }
  else { int s = (j - 2) >> 1; src = Ws + s * 1024 + (j & 1); bias = bs[s * 2 + (j & 1)]; }
  float acc = bias;
  for (int d = 0; d < DEMB; ++d) acc = fmaf(bb[d], src[2 * d], acc);
  bf[j] = acc;
}

// ---------- kernel 1: fused GEMM, 2-deep pipeline ----------
// 128x128 tile, BK=32, 2x2 waves (R6 body). NEW: stage/load for tile t+2
// (not t+1) each phase -> every load has ~2 phases (>1500cy) to land; barrier
// wait is counted vmcnt(6) = keep exactly {B(t+2):2, A(t+2):4} in flight.
// B: 3 LDS slots; A: 2 reg bufs + 2 LDS slots. s_setprio around MFMA (T5).
__global__ __launch_bounds__(256, 3) void gemm_fused(
    const float* __restrict__ x, const unsigned short* __restrict__ wbt,
    const float* __restrict__ bb, const int* __restrict__ sid,
    const float* __restrict__ bfold, float* __restrict__ out) {
  __shared__ __align__(16) char SM[40960];   // As0|As1 (8KB) | B0|B1|B2 (8KB)
  char* const As0 = SM;
  char* const As1 = SM + 8192;
  char* const B0  = SM + 16384;
  char* const B1  = SM + 24576;
  char* const B2  = SM + 32768;

  const int t = threadIdx.x;
  const int lane = t & 63;
  const int wid = t >> 6;
  const int wm = wid >> 1, wn = wid & 1;

  // XCD swizzle: 5120 blocks (%8==0); 5 consecutive swz share one mtile/XCD.
  const int bid = blockIdx.x;
  const int swz = (bid & 7) * 640 + (bid >> 3);
  const int mtile = swz / 5;
  const int ntile = swz - mtile * 5;
  const long m0 = (long)mtile * 128;
  const int n0 = ntile * 128;

  // ---- A staging (R6-proven): row = t>>3 (+32p), float4 kc = t&7 ----
  const int akc = t & 7;
  const int abyte = (t >> 3) * 64 + ((((akc >> 1) ^ ((t >> 4) & 3)) << 4)) + (akc & 1) * 8;
  const float* xbase = x + (m0 + (t >> 3)) * DIN + akc * 4;

  // ---- B staging (gload_lds, pre-swizzled source; R6-proven) ----
  const int bn = wid * 16 + (lane >> 2);
  const int bsg = (lane & 3) ^ ((lane >> 3) & 3);
  const unsigned short* bsrc = wbt + (long)(n0 + bn) * DIN + bsg * 8;

  // ---- fragment reads: granule = lg ^ ((l15>>1)&3), 64B rows ----
  const int l15 = lane & 15, lg = lane >> 4;
  const int kgo = ((lg ^ ((l15 >> 1) & 3)) << 4);
  const int ardrow = (wm * 64 + l15) * 64;
  const int brdrow = (wn * 64 + l15) * 64;

  f32x4 acc[4][4] = {};
  float4 areg0[4], areg1[4];

  auto loadA0 = [&](int k0) {
#pragma unroll
    for (int p = 0; p < 4; ++p)
      areg0[p] = *(const float4*)(xbase + (long)p * 32 * DIN + k0);
  };
  auto loadA1 = [&](int k0) {
#pragma unroll
    for (int p = 0; p < 4; ++p)
      areg1[p] = *(const float4*)(xbase + (long)p * 32 * DIN + k0);
  };
  auto stageB = [&](char* Bw, int k0) {
#pragma unroll
    for (int i = 0; i < 2; ++i) {
      const unsigned short* gp = bsrc + (long)i * 64 * DIN + k0;
      __builtin_amdgcn_global_load_lds(
          (const __attribute__((address_space(1))) void*)gp,
          (__attribute__((address_space(3))) void*)(Bw + i * 4096 + wid * 1024),
          16, 0, 0);
    }
  };
  auto writeA0 = [&](char* base) {   // from areg0
#pragma unroll
    for (int p = 0; p < 4; ++p) {
      uint2 v; v.x = pkhi(areg0[p].x, areg0[p].y); v.y = pkhi(areg0[p].z, areg0[p].w);
      *(uint2*)(base + abyte + p * 2048) = v;
    }
  };
  auto writeA1 = [&](char* base) {   // from areg1
#pragma unroll
    for (int p = 0; p < 4; ++p) {
      uint2 v; v.x = pkhi(areg1[p].x, areg1[p].y); v.y = pkhi(areg1[p].z, areg1[p].w);
      *(uint2*)(base + abyte + p * 2048) = v;
    }
  };
  auto compute = [&](const char* Ab, const char* Bb) {
    bf16x8 af[4], bfv[4];
#pragma unroll
    for (int i = 0; i < 4; ++i) {
      af[i] = *(const bf16x8*)(Ab + ardrow + i * 1024 + kgo);
      bfv[i] = *(const bf16x8*)(Bb + brdrow + i * 1024 + kgo);
    }
    __builtin_amdgcn_s_setprio(1);
#pragma unroll
    for (int mi = 0; mi < 4; ++mi)
#pragma unroll
      for (int ni = 0; ni < 4; ++ni)
        acc[mi][ni] = __builtin_amdgcn_mfma_f32_16x16x32_bf16(af[mi], bfv[ni],
                                                             acc[mi][ni], 0, 0, 0);
    __builtin_amdgcn_s_setprio(0);
  };

#define PH(BC, BW, AC, AW, LD, WR, TT)                              \
  stageB(BW, ((TT) + 2) * 32);                                      \
  LD(((TT) + 2) * 32);                                              \
  compute(AC, BC);                                                  \
  WR(AW);                                                           \
  __builtin_amdgcn_sched_barrier(0);                                \
  asm volatile("s_waitcnt vmcnt(6) lgkmcnt(0)" ::: "memory");       \
  __builtin_amdgcn_sched_barrier(0);                                \
  __builtin_amdgcn_s_barrier();

  // prologue: tiles 0,1 in flight; write A(0); keep {B(1),A(1)} flying
  stageB(B0, 0);
  loadA0(0);
  stageB(B1, 32);
  loadA1(32);
  writeA0(As0);                     // implicit vmcnt(6): waits exactly areg0
  __builtin_amdgcn_sched_barrier(0);
  asm volatile("s_waitcnt vmcnt(6) lgkmcnt(0)" ::: "memory");
  __builtin_amdgcn_sched_barrier(0);
  __builtin_amdgcn_s_barrier();

#pragma unroll 1
  for (int tb = 0; tb < 30; tb += 6) {
    PH(B0, B2, As0, As1, loadA0, writeA1, tb + 0)
    PH(B1, B0, As1, As0, loadA1, writeA0, tb + 1)
    PH(B2, B1, As0, As1, loadA0, writeA1, tb + 2)
    PH(B0, B2, As1, As0, loadA1, writeA0, tb + 3)
    PH(B1, B0, As0, As1, loadA0, writeA1, tb + 4)
    PH(B2, B1, As1, As0, loadA1, writeA0, tb + 5)
  }
#undef PH

  // t = 30: compute tile30; write A(31); full drain
  compute(As0, B0);
  writeA1(As1);
  __builtin_amdgcn_sched_barrier(0);
  asm volatile("s_waitcnt vmcnt(0) lgkmcnt(0)" ::: "memory");
  __builtin_amdgcn_sched_barrier(0);
  __builtin_amdgcn_s_barrier();
  // t = 31
  compute(As1, B1);

  // ---- epilogue (R6-verbatim) ----
  if (ntile < 4) {
    const int colg = n0 + wn * 64 + l15;
    float bbv[4];
#pragma unroll
    for (int ni = 0; ni < 4; ++ni) bbv[ni] = bb[colg + ni * 16];
#pragma unroll
    for (int mi = 0; mi < 4; ++mi) {
      const long rbase = m0 + wm * 64 + mi * 16 + lg * 4;
#pragma unroll
      for (int ni = 0; ni < 4; ++ni)
#pragma unroll
        for (int r = 0; r < 4; ++r)
          out[(rbase + r) * DEMB + colg + ni * 16] = acc[mi][ni][r] + bbv[ni];
    }
  } else {
    // head tile: acc cols 0..33 are x@Wfold; gather selected cols via LDS
    __syncthreads();
    float* hl = (float*)SM;          // [128][49] f32 = 25 KiB
    if (wn == 0) {
#pragma unroll
      for (int ni = 0; ni < 3; ++ni)
#pragma unroll
        for (int mi = 0; mi < 4; ++mi)
#pragma unroll
          for (int r = 0; r < 4; ++r) {
            int row = wm * 64 + mi * 16 + lg * 4 + r;
            hl[row * 49 + l15 + ni * 16] = acc[mi][ni][r];
          }
    }
    __syncthreads();
    if (t < 128) {
      const long row = m0 + t;
      const int s = sid[row];
      const float v0 = hl[t * 49 + 0] + bfold[0];
      const float v1 = hl[t * 49 + 1] + bfold[1];
      const float v2 = hl[t * 49 + 2 + 2 * s] + bfold[2 + 2 * s];
      const float v3 = hl[t * 49 + 3 + 2 * s] + bfold[3 + 2 * s];
      float* hp = out + NROWS * DEMB;
      hp[row] = v0;
      hp[NROWS + row] = softplusf(v1) + 0.001f;
      hp[2 * NROWS + row] = v2;
      hp[3 * NROWS + row] = softplusf(v3) + 0.001f;
    }
  }
}

extern "C" void kernel_launch(void* const* d_in, const int* in_sizes, int n_in,
                              void* d_out, int out_size, void* d_ws, size_t ws_size,
                              hipStream_t stream) {
  const float* x  = (const float*)d_in[0];
  const int* sid  = (const int*)d_in[1];
  const float* Wb = (const float*)d_in[2];
  const float* bb = (const float*)d_in[3];
  const float* Wp = (const float*)d_in[4];
  const float* bp = (const float*)d_in[5];
  const float* Ws = (const float*)d_in[6];
  const float* bs = (const float*)d_in[7];
  float* out = (float*)d_out;
  unsigned short* WbT = (unsigned short*)d_ws;            // 640*1024 bf16 = 1.25 MiB
  float* bfoldp = (float*)(WbT + (long)NEXT * DIN);       // 34 f32

  wb_transpose<<<256, 256, 0, stream>>>(Wb, WbT);
  zero_tail<<<188, 256, 0, stream>>>((unsigned*)(WbT + 546 * DIN));
  wfold_rows<<<256, 256, 0, stream>>>(Wb, Wp, Ws, WbT);
  bfold_k<<<1, 64, 0, stream>>>(bb, Wp, bp, Ws, bs, bfoldp);
  gemm_fused<<<5120, 256, 0, stream>>>(x, WbT, bb, sid, bfoldp, out);
}